// Round 8
// baseline (188.709 us; speedup 1.0000x reference)
//
#include <hip/hip_runtime.h>

// SolventAccessibility — R8: pack-then-scan, zero global atomics, XCD-aware.
// R7 counters: k_scan FETCH 102.8 MB vs 32 MB unique — the 8 chunk-blocks of a
// slice sat on 8 different XCDs (c = blockIdx%8), each re-fetching contRat.
// R8: (1) c = blockIdx/S so XCD = s%8 -> slice-sharing blocks on ONE XCD's L2;
// (2) seq scattered stores deleted — scan ORs (am<<5|resname) into an LDS
// plane, reduce ORs across slices; (3) reduce = 1 thread/residue, 6 bins.

#define PADV   (-999)
#define BATCH  8
#define NCHAIN 2
#define SEQL   1024
#define NALT   3
#define NRES   20
#define NATOMS 2000000
#define GLY    7
#define NRESID (BATCH * NCHAIN * SEQL)       // 16384 residues
#define NBINS  (NRESID * NALT)               // 49152 bins per output tensor
#define NCHUNK 8                             // residue chunks
#define CHSZ   (NRESID / NCHUNK)             // 2048 residues/chunk
#define SMAXSL 64                            // max atom slices (multiple of 8)

// pack word: r[13:0] | resname[18:14] | bb[19] | altmask[22:20]
#define PK_R(w)    ((int)((w) & 16383u))
#define PK_RES(w)  (((w) >> 14) & 31u)
#define PK_BB(w)   (((w) >> 19) & 1u)
#define PK_AM(w)   ((w) >> 20)

// ---------------------------------------------------------------------------
// pack: 4 atoms/thread, pure streaming transform (no scattered stores).
// Per-wave alternatives-layout detection: int32 0/1 little-endian has byte==0
// at offsets !=0 (mod 4); np.bool_ is ~70% nonzero there (P(miss) ~ 0.3^64).
// ---------------------------------------------------------------------------
__global__ __launch_bounds__(256)
void k_pack(const int* __restrict__ desc,            // [NATOMS][5]
            const unsigned char* __restrict__ altB,
            const int* __restrict__ altI,
            unsigned* __restrict__ pack) {
    const unsigned char probe = altB[(threadIdx.x & 63) * 4 + 1];
    const bool byteLayout = (__ballot(probe != 0) != 0ULL);

    const int t  = blockIdx.x * blockDim.x + threadIdx.x;
    const int a0 = t * 4;
    if (a0 >= NATOMS) return;

    // 4 desc rows = 20 ints = 5 aligned int4 loads
    const int4* d4 = (const int4*)(desc + (size_t)a0 * 5);
    int4 q0 = d4[0], q1 = d4[1], q2 = d4[2], q3 = d4[3], q4 = d4[4];
    int an[4], rn[4], ch[4], bi[4], rs[4];
    an[0]=q0.x; rn[0]=q0.y; ch[0]=q0.z; bi[0]=q0.w; rs[0]=q1.x;
    an[1]=q1.y; rn[1]=q1.z; ch[1]=q1.w; bi[1]=q2.x; rs[1]=q2.y;
    an[2]=q2.z; rn[2]=q2.w; ch[2]=q3.x; bi[2]=q3.y; rs[2]=q3.z;
    an[3]=q3.w; rn[3]=q4.x; ch[3]=q4.y; bi[3]=q4.z; rs[3]=q4.w;

    unsigned am[4];
    if (byteLayout) {
        const unsigned* b3 = (const unsigned*)(altB + (size_t)a0 * 3);  // 12 B
        unsigned w0 = b3[0], w1 = b3[1], w2 = b3[2];
        unsigned char f[12];
        f[0]=w0; f[1]=w0>>8; f[2]=w0>>16; f[3]=w0>>24;
        f[4]=w1; f[5]=w1>>8; f[6]=w1>>16; f[7]=w1>>24;
        f[8]=w2; f[9]=w2>>8; f[10]=w2>>16; f[11]=w2>>24;
        #pragma unroll
        for (int k = 0; k < 4; ++k)
            am[k] = (f[k*3+0]?1u:0u) | (f[k*3+1]?2u:0u) | (f[k*3+2]?4u:0u);
    } else {
        const int4* i4 = (const int4*)(altI + (size_t)a0 * 3);          // 48 B
        int4 w0 = i4[0], w1 = i4[1], w2 = i4[2];
        int f[12] = {w0.x,w0.y,w0.z,w0.w, w1.x,w1.y,w1.z,w1.w,
                     w2.x,w2.y,w2.z,w2.w};
        #pragma unroll
        for (int k = 0; k < 4; ++k)
            am[k] = (f[k*3+0]?1u:0u) | (f[k*3+1]?2u:0u) | (f[k*3+2]?4u:0u);
    }

    uint4 pw;
    unsigned* pwp = (unsigned*)&pw;
    #pragma unroll
    for (int k = 0; k < 4; ++k) {
        const bool valid = (an[k] != PADV);
        const bool bb    = ((unsigned)an[k] <= 3u);   // BACKBONE = {0,1,2,3}
        const int  r     = (bi[k] * NCHAIN + ch[k]) * SEQL + rn[k];
        const bool rOK   = ((unsigned)r < (unsigned)NRESID);
        const unsigned a = (valid && rOK) ? am[k] : 0u;
        pwp[k] = (rOK ? (unsigned)r : 0u) | ((unsigned)(rs[k] & 31) << 14)
               | ((bb ? 1u : 0u) << 19) | (a << 20);
    }
    *(uint4*)(pack + a0) = pw;
}

// ---------------------------------------------------------------------------
// scan: c = blockIdx/S (chunk), s = blockIdx%S (slice). With S%8==0 and
// round-robin block->XCD dispatch, all 8 chunk-blocks of slice s share one
// XCD's L2 (contRat+pack slice fetched once).
// LDS: 6 float planes (48 KB) + resInfo OR-plane (8 KB) = 56 KB.
// part: [S][6][NRESID] f32. partRes: [S][NRESID] u8.
// ---------------------------------------------------------------------------
__global__ __launch_bounds__(1024)
void k_scan(const float* __restrict__ contRat,       // [NATOMS][NALT]
            const unsigned* __restrict__ pack,
            float* __restrict__ part,
            unsigned char* __restrict__ partRes,
            int S, int sliceSz) {
    __shared__ float acc[6 * CHSZ];                  // 48 KB
    __shared__ unsigned resOr[CHSZ];                 // 8 KB

    const int c = blockIdx.x / S;
    const int s = blockIdx.x - c * S;

    for (int j = threadIdx.x; j < 6 * CHSZ; j += blockDim.x) acc[j] = 0.0f;
    for (int j = threadIdx.x; j < CHSZ; j += blockDim.x) resOr[j] = 0u;
    __syncthreads();

    const int start = s * sliceSz;
    int end = start + sliceSz;
    if (end > NATOMS) end = NATOMS;

    int i = start + (int)threadIdx.x * 4;
    const int step = (int)blockDim.x * 4;

    #define PROCESS(w, idx)                                                   \
        do {                                                                  \
            const unsigned am_ = PK_AM(w);                                    \
            if (am_) {                                                        \
                const int r_ = PK_R(w);                                       \
                if ((r_ >> 11) == c) {                                        \
                    const int lr_ = r_ & (CHSZ - 1);                          \
                    const float* cr_ = contRat + (size_t)(idx) * 3;           \
                    if (PK_BB(w)) {                                           \
                        atomicOr(&resOr[lr_], (am_ << 5) | PK_RES(w));        \
                        if (am_ & 1) atomicAdd(&acc[0 * CHSZ + lr_], cr_[0]); \
                        if (am_ & 2) atomicAdd(&acc[1 * CHSZ + lr_], cr_[1]); \
                        if (am_ & 4) atomicAdd(&acc[2 * CHSZ + lr_], cr_[2]); \
                    } else {                                                  \
                        if (am_ & 1) atomicAdd(&acc[3 * CHSZ + lr_], cr_[0]); \
                        if (am_ & 2) atomicAdd(&acc[4 * CHSZ + lr_], cr_[1]); \
                        if (am_ & 4) atomicAdd(&acc[5 * CHSZ + lr_], cr_[2]); \
                    }                                                         \
                }                                                             \
            }                                                                 \
        } while (0)

    for (; i + 3 < end; i += step) {
        const uint4 w4 = *(const uint4*)(pack + i);
        PROCESS(w4.x, i);
        PROCESS(w4.y, i + 1);
        PROCESS(w4.z, i + 2);
        PROCESS(w4.w, i + 3);
    }
    for (int k = i; k < end && k < i + 4; ++k) PROCESS(pack[k], k);
    #undef PROCESS

    __syncthreads();

    for (int t = threadIdx.x; t < 6 * CHSZ; t += blockDim.x) {
        const int plane = t >> 11;
        const int j     = t & (CHSZ - 1);
        part[((size_t)s * 6 + plane) * NRESID + c * CHSZ + j] = acc[t];
    }
    for (int j = threadIdx.x; j < CHSZ; j += blockDim.x)
        partRes[(size_t)s * NRESID + c * CHSZ + j] = (unsigned char)resOr[j];
}

// ---------------------------------------------------------------------------
// reduce: 1 thread per residue -> 6 outputs. plane MC = alt, SC = 3+alt.
// ---------------------------------------------------------------------------
__global__ __launch_bounds__(256)
void k_reduce(const float* __restrict__ part,
              const unsigned char* __restrict__ partRes, int S,
              float* __restrict__ out,      // [2*NBINS]
              const float* __restrict__ mcmax,
              const float* __restrict__ mcmin,
              const float* __restrict__ scmax,
              const float* __restrict__ scmin) {
    const int r = blockIdx.x * blockDim.x + threadIdx.x;
    if (r >= NRESID) return;

    float m0 = 0.f, m1 = 0.f, m2 = 0.f, v0 = 0.f, v1 = 0.f, v2 = 0.f;
    unsigned rb = 0;
    for (int s = 0; s < S; ++s) {
        const float* b = part + (size_t)s * 6 * NRESID + r;
        m0 += b[0 * NRESID]; m1 += b[1 * NRESID]; m2 += b[2 * NRESID];
        v0 += b[3 * NRESID]; v1 += b[4 * NRESID]; v2 += b[5 * NRESID];
        rb |= partRes[(size_t)s * NRESID + r];
    }

    const unsigned am = rb >> 5;
    int resn = (int)(rb & 31u);
    if (resn > NRES - 1) resn = NRES - 1;
    const float mLo = mcmin[resn], mSpan = mcmax[resn] - mLo;
    const float sLo = scmin[resn], sSpan = scmax[resn] - sLo;
    const bool  gly = ((rb & 31u) == GLY);

    float mv[3] = {m0, m1, m2}, vv[3] = {v0, v1, v2};
    #pragma unroll
    for (int alt = 0; alt < 3; ++alt) {
        float m = mv[alt], v = vv[alt];
        if ((am >> alt) & 1u) {
            m = (m - mLo) / mSpan;
            v = gly ? 0.0f : (v - sLo) / sSpan;
        }
        out[r * 3 + alt]         = fminf(fmaxf(m, 0.0f), 1.0f);
        out[NBINS + r * 3 + alt] = fminf(fmaxf(v, 0.0f), 1.0f);
    }
}

// ---------------------------------------------------------------------------
// Fallback (tiny ws): flat agent-scope atomics (proven R1).
// ---------------------------------------------------------------------------
__global__ void k_init_flat(float* __restrict__ out, int* __restrict__ seq,
                            int* __restrict__ flag,
                            const unsigned char* __restrict__ altBytes) {
    int i = blockIdx.x * blockDim.x + threadIdx.x;
    if (i < NBINS) { out[i] = 0.0f; out[NBINS + i] = 0.0f; seq[i] = PADV; }
    if (blockIdx.x == 0 && threadIdx.x < 64) {
        unsigned char b = altBytes[threadIdx.x * 4 + 1];
        unsigned long long m = __ballot(b != 0);
        if (threadIdx.x == 0) *flag = (m != 0ULL) ? 1 : 0;
    }
}

__global__ void k_scatter_flat(const float* __restrict__ contRat,
                               const int* __restrict__ desc,
                               const unsigned char* __restrict__ altB,
                               const int* __restrict__ altI,
                               const int* __restrict__ flag,
                               float* __restrict__ mcArr,
                               float* __restrict__ scArr,
                               int* __restrict__ seq) {
    int a = blockIdx.x * blockDim.x + threadIdx.x;
    if (a >= NATOMS) return;
    const int atname  = desc[a * 5 + 0];
    const int resnum  = desc[a * 5 + 1];
    const int chain   = desc[a * 5 + 2];
    const int batchI  = desc[a * 5 + 3];
    const int resname = desc[a * 5 + 4];
    const bool valid = (atname != PADV);
    const bool is_bb = (atname >= 0) && (atname <= 3);
    const int  base  = ((batchI * NCHAIN + chain) * SEQL + resnum) * NALT;
    const bool byteLayout = (*flag != 0);
    #pragma unroll
    for (int alt = 0; alt < NALT; ++alt) {
        bool altv;
        if (byteLayout) altv = (altB[a * NALT + alt] != 0);
        else            altv = (altI[a * NALT + alt] != 0);
        if (altv && valid) {
            const float c = contRat[a * NALT + alt];
            const int   f = base + alt;
            if (is_bb) { atomicAdd(&mcArr[f], c); seq[f] = resname; }
            else       { atomicAdd(&scArr[f], c); }
        }
    }
}

__global__ void k_final_flat(float* __restrict__ mc, float* __restrict__ sc,
                             const int* __restrict__ seq,
                             const float* __restrict__ mcmax,
                             const float* __restrict__ mcmin,
                             const float* __restrict__ scmax,
                             const float* __restrict__ scmin) {
    int i = blockIdx.x * blockDim.x + threadIdx.x;
    if (i >= NBINS) return;
    const int s = seq[i];
    float m = mc[i], v = sc[i];
    if (s != PADV) {
        int idx = s < 0 ? 0 : (s > NRES - 1 ? NRES - 1 : s);
        m = (m - mcmin[idx]) / (mcmax[idx] - mcmin[idx]);
        if (s != GLY) v = (v - scmin[idx]) / (scmax[idx] - scmin[idx]);
        else          v = 0.0f;
    }
    mc[i] = fminf(fmaxf(m, 0.0f), 1.0f);
    sc[i] = fminf(fmaxf(v, 0.0f), 1.0f);
}

// ---------------------------------------------------------------------------
extern "C" void kernel_launch(void* const* d_in, const int* in_sizes, int n_in,
                              void* d_out, int out_size, void* d_ws, size_t ws_size,
                              hipStream_t stream) {
    const float* contRat = (const float*)d_in[0];
    const float* mcmax   = (const float*)d_in[1];
    const float* mcmin   = (const float*)d_in[2];
    const float* scmax   = (const float*)d_in[3];
    const float* scmin   = (const float*)d_in[4];
    const int*   desc    = (const int*)d_in[5];
    const void*  alts    = d_in[6];

    float* out = (float*)d_out;

    const size_t packBytes  = (size_t)NATOMS * sizeof(unsigned);       // 8 MB
    const size_t sliceBytes = (size_t)6 * NRESID * sizeof(float)       // 384 KB
                            + (size_t)NRESID;                          // +16 KB res

    int S = 0;
    if (ws_size > packBytes + 64) {
        size_t s = (ws_size - packBytes - 64) / sliceBytes;
        S = (s > SMAXSL) ? SMAXSL : (int)s;
        S &= ~7;                                      // multiple of 8 (XCD map)
    }

    if (S >= 8) {
        unsigned*      pack    = (unsigned*)d_ws;
        float*         part    = (float*)((char*)d_ws + packBytes);
        unsigned char* partRes = (unsigned char*)((char*)d_ws + packBytes +
                                 (size_t)S * 6 * NRESID * sizeof(float));

        int sliceSz = (NATOMS + S - 1) / S;
        sliceSz = (sliceSz + 3) & ~3;                 // keep uint4 alignment

        k_pack<<<(NATOMS / 4 + 255) / 256, 256, 0, stream>>>(
            desc, (const unsigned char*)alts, (const int*)alts, pack);
        k_scan<<<NCHUNK * S, 1024, 0, stream>>>(
            contRat, pack, part, partRes, S, sliceSz);
        k_reduce<<<(NRESID + 255) / 256, 256, 0, stream>>>(
            part, partRes, S, out, mcmax, mcmin, scmax, scmin);
    } else {
        // ws too small: flat agent-scope atomic path
        int* seq  = (int*)d_ws;
        int* flag = seq + NBINS;
        const int binBlocks = (NBINS + 255) / 256;
        k_init_flat<<<binBlocks, 256, 0, stream>>>(out, seq, flag,
                                                   (const unsigned char*)alts);
        k_scatter_flat<<<(NATOMS + 255) / 256, 256, 0, stream>>>(
            contRat, desc,
            (const unsigned char*)alts, (const int*)alts, flag,
            out, out + NBINS, seq);
        k_final_flat<<<binBlocks, 256, 0, stream>>>(
            out, out + NBINS, seq, mcmax, mcmin, scmax, scmin);
    }
}

// Round 10
// 170.115 us; speedup vs baseline: 1.1093x; 1.1093x over previous
//
#include <hip/hip_runtime.h>

// SolventAccessibility — R10 = R9 resubmission (R9 hit a GPU-acquisition
// timeout; no kernel evidence). Counting-sort pipeline, zero global atomics.
// R8 evidence: chunked LDS scan was issue/latency-bound on 8x-redundant pack
// scanning + scattered contRat gathers (FETCH fix gave no time back).
// Design: sort atoms by residue bucket (256 buckets x 64 residues), then each
// accumulation block streams ITS OWN segment once, LDS tile = 1.5 KB.
// Phases: pack+hist -> prefix (2) -> scatter (LDS-reserved slots) ->
// accumulate (2048 blocks) -> finalize (fused normalize+clip).

#define PADV   (-999)
#define BATCH  8
#define NCHAIN 2
#define SEQL   1024
#define NALT   3
#define NRES   20
#define NATOMS 2000000
#define GLY    7
#define NRESID (BATCH * NCHAIN * SEQL)       // 16384 residues
#define NBINS  (NRESID * NALT)               // 49152 bins per output tensor
#define NBLK   ((NATOMS + 1023) / 1024)      // 1954 pack/scatter blocks
#define NBUCK  256                           // residue buckets
#define ACC_SUB 8                            // sub-blocks per bucket in accum

// pack word: r[13:0] | resname[18:14] | bb[19] | altmask[22:20]
#define PK_R(w)    ((int)((w) & 16383u))
#define PK_RES(w)  (((w) >> 14) & 31u)
#define PK_BB(w)   (((w) >> 19) & 1u)
#define PK_AM(w)   ((w) >> 20)

// workspace layout (bytes)
#define OFF_PACK  ((size_t)0)
#define SZ_PACK   ((size_t)NATOMS * 4)                    //  8,000,000
#define OFF_HIST  (OFF_PACK + SZ_PACK)
#define SZ_HIST   ((size_t)NBUCK * NBLK * 4)              //  2,000,896
#define OFF_BB    (OFF_HIST + SZ_HIST)
#define SZ_BB     ((size_t)1280)                          //  257 u32, padded
#define OFF_TOT   (OFF_BB + SZ_BB)
#define SZ_TOT    ((size_t)1024)                          //  256 u32
#define OFF_SORT  (OFF_TOT + SZ_TOT)
#define SZ_SORT   ((size_t)NATOMS * 8)                    // 16,000,000
#define OFF_ACC   (OFF_SORT + SZ_SORT)
#define SZ_ACC    ((size_t)NBUCK * ACC_SUB * 384 * 4)     //  3,145,728
#define OFF_RES   (OFF_ACC + SZ_ACC)
#define SZ_RES    ((size_t)NBUCK * ACC_SUB * 64 * 4)      //    524,288
#define WS_NEED   (OFF_RES + SZ_RES)                      // ~29.7 MB

// ---------------------------------------------------------------------------
// Phase 1: pack 4 atoms/thread + per-block bucket histogram.
// alternatives layout detection per-wave: int32 0/1 LE has byte==0 at offsets
// !=0 (mod 4); np.bool_ is ~70% nonzero there (P(all 64 zero) ~ 0.3^64).
// ---------------------------------------------------------------------------
__global__ __launch_bounds__(256)
void k_pack_hist(const int* __restrict__ desc,            // [NATOMS][5]
                 const unsigned char* __restrict__ altB,
                 const int* __restrict__ altI,
                 unsigned* __restrict__ pack,
                 unsigned* __restrict__ hist) {           // [NBUCK][NBLK]
    __shared__ unsigned h[NBUCK];
    for (int j = threadIdx.x; j < NBUCK; j += 256) h[j] = 0u;
    __syncthreads();

    const unsigned char probe = altB[(threadIdx.x & 63) * 4 + 1];
    const bool byteLayout = (__ballot(probe != 0) != 0ULL);

    const int a0 = (blockIdx.x * 256 + threadIdx.x) * 4;
    if (a0 < NATOMS) {                     // NATOMS%4==0 -> a0+3 also valid
        const int4* d4 = (const int4*)(desc + (size_t)a0 * 5);
        int4 q0 = d4[0], q1 = d4[1], q2 = d4[2], q3 = d4[3], q4 = d4[4];
        int an[4], rn[4], ch[4], bi[4], rs[4];
        an[0]=q0.x; rn[0]=q0.y; ch[0]=q0.z; bi[0]=q0.w; rs[0]=q1.x;
        an[1]=q1.y; rn[1]=q1.z; ch[1]=q1.w; bi[1]=q2.x; rs[1]=q2.y;
        an[2]=q2.z; rn[2]=q2.w; ch[2]=q3.x; bi[2]=q3.y; rs[2]=q3.z;
        an[3]=q3.w; rn[3]=q4.x; ch[3]=q4.y; bi[3]=q4.z; rs[3]=q4.w;

        unsigned am[4];
        if (byteLayout) {
            const unsigned* b3 = (const unsigned*)(altB + (size_t)a0 * 3);
            unsigned w0 = b3[0], w1 = b3[1], w2 = b3[2];
            unsigned char f[12];
            f[0]=w0; f[1]=w0>>8; f[2]=w0>>16; f[3]=w0>>24;
            f[4]=w1; f[5]=w1>>8; f[6]=w1>>16; f[7]=w1>>24;
            f[8]=w2; f[9]=w2>>8; f[10]=w2>>16; f[11]=w2>>24;
            #pragma unroll
            for (int k = 0; k < 4; ++k)
                am[k] = (f[k*3+0]?1u:0u) | (f[k*3+1]?2u:0u) | (f[k*3+2]?4u:0u);
        } else {
            const int4* i4 = (const int4*)(altI + (size_t)a0 * 3);
            int4 w0 = i4[0], w1 = i4[1], w2 = i4[2];
            int f[12] = {w0.x,w0.y,w0.z,w0.w, w1.x,w1.y,w1.z,w1.w,
                         w2.x,w2.y,w2.z,w2.w};
            #pragma unroll
            for (int k = 0; k < 4; ++k)
                am[k] = (f[k*3+0]?1u:0u) | (f[k*3+1]?2u:0u) | (f[k*3+2]?4u:0u);
        }

        uint4 pw;
        unsigned* pwp = (unsigned*)&pw;
        #pragma unroll
        for (int k = 0; k < 4; ++k) {
            const bool valid = (an[k] != PADV);
            const bool bb    = ((unsigned)an[k] <= 3u);   // BACKBONE {0,1,2,3}
            const int  r     = (bi[k] * NCHAIN + ch[k]) * SEQL + rn[k];
            const bool rOK   = ((unsigned)r < (unsigned)NRESID);
            const unsigned a = (valid && rOK) ? am[k] : 0u;
            pwp[k] = (rOK ? (unsigned)r : 0u)
                   | ((unsigned)(rs[k] & 31) << 14)
                   | ((bb ? 1u : 0u) << 19) | (a << 20);
            if (a) atomicAdd(&h[(pwp[k] >> 6) & 255u], 1u);
        }
        *(uint4*)(pack + a0) = pw;
    }
    __syncthreads();
    for (int j = threadIdx.x; j < NBUCK; j += 256)
        hist[(size_t)j * NBLK + blockIdx.x] = h[j];
}

// ---------------------------------------------------------------------------
// Phase 2a: per-bucket exclusive scan over NBLK block counts (in place);
// writes bucket totals.
// ---------------------------------------------------------------------------
__global__ __launch_bounds__(256)
void k_prefix1(unsigned* __restrict__ hist, unsigned* __restrict__ totals) {
    __shared__ unsigned cnt[2048];
    __shared__ unsigned csum[256];
    unsigned* h = hist + (size_t)blockIdx.x * NBLK;
    const int t = threadIdx.x;

    for (int j = t; j < 2048; j += 256) cnt[j] = (j < NBLK) ? h[j] : 0u;
    __syncthreads();

    unsigned s = 0;
    #pragma unroll
    for (int k = 0; k < 8; ++k) s += cnt[t * 8 + k];
    csum[t] = s;
    __syncthreads();
    for (int off = 1; off < 256; off <<= 1) {
        unsigned x = (t >= off) ? csum[t - off] : 0u;
        __syncthreads();
        csum[t] += x;
        __syncthreads();
    }
    if (t == 255) totals[blockIdx.x] = csum[255];
    unsigned run = (t == 0) ? 0u : csum[t - 1];
    #pragma unroll
    for (int k = 0; k < 8; ++k) {
        const int idx = t * 8 + k;
        const unsigned old = cnt[idx];
        cnt[idx] = run;
        run += old;
    }
    __syncthreads();
    for (int j = t; j < NBLK; j += 256) h[j] = cnt[j];
}

// ---------------------------------------------------------------------------
// Phase 2b: exclusive scan of bucket totals -> bucketBase[257].
// ---------------------------------------------------------------------------
__global__ __launch_bounds__(256)
void k_prefix2(const unsigned* __restrict__ totals,
               unsigned* __restrict__ bucketBase) {
    __shared__ unsigned s[256];
    const int t = threadIdx.x;
    const unsigned own = totals[t];
    s[t] = own;
    __syncthreads();
    for (int off = 1; off < 256; off <<= 1) {
        unsigned x = (t >= off) ? s[t - off] : 0u;
        __syncthreads();
        s[t] += x;
        __syncthreads();
    }
    bucketBase[t] = s[t] - own;
    if (t == 255) bucketBase[256] = s[255];
}

// ---------------------------------------------------------------------------
// Phase 3: scatter {pack, atomIdx} to sorted positions. Slots come from
// LDS counters over pre-reserved disjoint per-(block,bucket) ranges.
// ---------------------------------------------------------------------------
__global__ __launch_bounds__(256)
void k_scatter(const unsigned* __restrict__ pack,
               const unsigned* __restrict__ hist,
               const unsigned* __restrict__ bucketBase,
               uint2* __restrict__ sorted) {
    __shared__ unsigned lbase[NBUCK];
    for (int j = threadIdx.x; j < NBUCK; j += 256)
        lbase[j] = bucketBase[j] + hist[(size_t)j * NBLK + blockIdx.x];
    __syncthreads();

    const int a0 = (blockIdx.x * 256 + threadIdx.x) * 4;
    if (a0 < NATOMS) {
        const uint4 pw = *(const uint4*)(pack + a0);
        const unsigned* pwp = (const unsigned*)&pw;
        #pragma unroll
        for (int k = 0; k < 4; ++k) {
            const unsigned w = pwp[k];
            if (w >> 20) {
                const unsigned b   = (w >> 6) & 255u;
                const unsigned pos = atomicAdd(&lbase[b], 1u);
                sorted[pos] = make_uint2(w, (unsigned)(a0 + k));
            }
        }
    }
}

// ---------------------------------------------------------------------------
// Phase 4: accumulate. block = (bucket b, sub s). LDS: 64 res x 6 planes.
// ---------------------------------------------------------------------------
__global__ __launch_bounds__(256)
void k_accum(const uint2* __restrict__ sorted,
             const float* __restrict__ contRat,
             const unsigned* __restrict__ bucketBase,
             float* __restrict__ accPart,          // [NBUCK][ACC_SUB][6][64]
             unsigned* __restrict__ resPart) {     // [NBUCK][ACC_SUB][64]
    __shared__ float acc[6 * 64];
    __shared__ unsigned ror[64];
    const int b   = blockIdx.x >> 3;
    const int sub = blockIdx.x & 7;

    for (int j = threadIdx.x; j < 384; j += 256) acc[j] = 0.0f;
    if (threadIdx.x < 64) ror[threadIdx.x] = 0u;
    __syncthreads();

    const unsigned s0 = bucketBase[b], s1 = bucketBase[b + 1];
    const unsigned len = s1 - s0;
    const unsigned lo = s0 + (unsigned)(((unsigned long long)len * sub) >> 3);
    const unsigned hi = s0 + (unsigned)(((unsigned long long)len * (sub + 1)) >> 3);

    for (unsigned i = lo + threadIdx.x; i < hi; i += 256) {
        const uint2 e = sorted[i];
        const unsigned w = e.x;
        const int lr = (int)(w & 63u);
        const unsigned am = PK_AM(w);
        const float* cr = contRat + (size_t)e.y * 3;
        const int pb = PK_BB(w) ? 0 : 3;
        if (PK_BB(w)) atomicOr(&ror[lr], (am << 5) | PK_RES(w));
        if (am & 1) atomicAdd(&acc[(pb + 0) * 64 + lr], cr[0]);
        if (am & 2) atomicAdd(&acc[(pb + 1) * 64 + lr], cr[1]);
        if (am & 4) atomicAdd(&acc[(pb + 2) * 64 + lr], cr[2]);
    }
    __syncthreads();

    float* ap = accPart + ((size_t)b * ACC_SUB + sub) * 384;
    for (int j = threadIdx.x; j < 384; j += 256) ap[j] = acc[j];
    if (threadIdx.x < 64)
        resPart[((size_t)b * ACC_SUB + sub) * 64 + threadIdx.x] = ror[threadIdx.x];
}

// ---------------------------------------------------------------------------
// Phase 5: finalize. block b, thread t = lr*3+alt -> out[b*192+t] contiguous.
// ---------------------------------------------------------------------------
__global__ __launch_bounds__(192)
void k_finalize(const float* __restrict__ accPart,
                const unsigned* __restrict__ resPart,
                float* __restrict__ out,
                const float* __restrict__ mcmax,
                const float* __restrict__ mcmin,
                const float* __restrict__ scmax,
                const float* __restrict__ scmin) {
    const int b = blockIdx.x;
    const int t = threadIdx.x;            // 0..191
    const int lr = t / 3, alt = t - lr * 3;

    float m = 0.0f, v = 0.0f;
    unsigned rb = 0u;
    #pragma unroll
    for (int s = 0; s < ACC_SUB; ++s) {
        const float* ap = accPart + ((size_t)b * ACC_SUB + s) * 384;
        m  += ap[alt * 64 + lr];
        v  += ap[(3 + alt) * 64 + lr];
        rb |= resPart[((size_t)b * ACC_SUB + s) * 64 + lr];
    }

    if ((rb >> (5 + alt)) & 1u) {
        int resn = (int)(rb & 31u);
        if (resn > NRES - 1) resn = NRES - 1;
        m = (m - mcmin[resn]) / (mcmax[resn] - mcmin[resn]);
        v = ((rb & 31u) == GLY) ? 0.0f
                                : (v - scmin[resn]) / (scmax[resn] - scmin[resn]);
    }
    out[b * 192 + t]         = fminf(fmaxf(m, 0.0f), 1.0f);
    out[NBINS + b * 192 + t] = fminf(fmaxf(v, 0.0f), 1.0f);
}

// ---------------------------------------------------------------------------
// Fallback (tiny ws): flat agent-scope atomics (proven R1).
// ---------------------------------------------------------------------------
__global__ void k_init_flat(float* __restrict__ out, int* __restrict__ seq,
                            int* __restrict__ flag,
                            const unsigned char* __restrict__ altBytes) {
    int i = blockIdx.x * blockDim.x + threadIdx.x;
    if (i < NBINS) { out[i] = 0.0f; out[NBINS + i] = 0.0f; seq[i] = PADV; }
    if (blockIdx.x == 0 && threadIdx.x < 64) {
        unsigned char b = altBytes[threadIdx.x * 4 + 1];
        unsigned long long m = __ballot(b != 0);
        if (threadIdx.x == 0) *flag = (m != 0ULL) ? 1 : 0;
    }
}

__global__ void k_scatter_flat(const float* __restrict__ contRat,
                               const int* __restrict__ desc,
                               const unsigned char* __restrict__ altB,
                               const int* __restrict__ altI,
                               const int* __restrict__ flag,
                               float* __restrict__ mcArr,
                               float* __restrict__ scArr,
                               int* __restrict__ seq) {
    int a = blockIdx.x * blockDim.x + threadIdx.x;
    if (a >= NATOMS) return;
    const int atname  = desc[a * 5 + 0];
    const int resnum  = desc[a * 5 + 1];
    const int chain   = desc[a * 5 + 2];
    const int batchI  = desc[a * 5 + 3];
    const int resname = desc[a * 5 + 4];
    const bool valid = (atname != PADV);
    const bool is_bb = (atname >= 0) && (atname <= 3);
    const int  base  = ((batchI * NCHAIN + chain) * SEQL + resnum) * NALT;
    const bool byteLayout = (*flag != 0);
    #pragma unroll
    for (int alt = 0; alt < NALT; ++alt) {
        bool altv;
        if (byteLayout) altv = (altB[a * NALT + alt] != 0);
        else            altv = (altI[a * NALT + alt] != 0);
        if (altv && valid) {
            const float c = contRat[a * NALT + alt];
            const int   f = base + alt;
            if (is_bb) { atomicAdd(&mcArr[f], c); seq[f] = resname; }
            else       { atomicAdd(&scArr[f], c); }
        }
    }
}

__global__ void k_final_flat(float* __restrict__ mc, float* __restrict__ sc,
                             const int* __restrict__ seq,
                             const float* __restrict__ mcmax,
                             const float* __restrict__ mcmin,
                             const float* __restrict__ scmax,
                             const float* __restrict__ scmin) {
    int i = blockIdx.x * blockDim.x + threadIdx.x;
    if (i >= NBINS) return;
    const int s = seq[i];
    float m = mc[i], v = sc[i];
    if (s != PADV) {
        int idx = s < 0 ? 0 : (s > NRES - 1 ? NRES - 1 : s);
        m = (m - mcmin[idx]) / (mcmax[idx] - mcmin[idx]);
        if (s != GLY) v = (v - scmin[idx]) / (scmax[idx] - scmin[idx]);
        else          v = 0.0f;
    }
    mc[i] = fminf(fmaxf(m, 0.0f), 1.0f);
    sc[i] = fminf(fmaxf(v, 0.0f), 1.0f);
}

// ---------------------------------------------------------------------------
extern "C" void kernel_launch(void* const* d_in, const int* in_sizes, int n_in,
                              void* d_out, int out_size, void* d_ws, size_t ws_size,
                              hipStream_t stream) {
    const float* contRat = (const float*)d_in[0];
    const float* mcmax   = (const float*)d_in[1];
    const float* mcmin   = (const float*)d_in[2];
    const float* scmax   = (const float*)d_in[3];
    const float* scmin   = (const float*)d_in[4];
    const int*   desc    = (const int*)d_in[5];
    const void*  alts    = d_in[6];

    float* out = (float*)d_out;

    if (ws_size >= WS_NEED) {
        unsigned* pack  = (unsigned*)((char*)d_ws + OFF_PACK);
        unsigned* hist  = (unsigned*)((char*)d_ws + OFF_HIST);
        unsigned* bbase = (unsigned*)((char*)d_ws + OFF_BB);
        unsigned* tot   = (unsigned*)((char*)d_ws + OFF_TOT);
        uint2*    sorted= (uint2*)   ((char*)d_ws + OFF_SORT);
        float*    accP  = (float*)   ((char*)d_ws + OFF_ACC);
        unsigned* resP  = (unsigned*)((char*)d_ws + OFF_RES);

        k_pack_hist<<<NBLK, 256, 0, stream>>>(
            desc, (const unsigned char*)alts, (const int*)alts, pack, hist);
        k_prefix1<<<NBUCK, 256, 0, stream>>>(hist, tot);
        k_prefix2<<<1, 256, 0, stream>>>(tot, bbase);
        k_scatter<<<NBLK, 256, 0, stream>>>(pack, hist, bbase, sorted);
        k_accum<<<NBUCK * ACC_SUB, 256, 0, stream>>>(
            sorted, contRat, bbase, accP, resP);
        k_finalize<<<NBUCK, 192, 0, stream>>>(
            accP, resP, out, mcmax, mcmin, scmax, scmin);
    } else {
        // ws too small: flat agent-scope atomic path
        int* seq  = (int*)d_ws;
        int* flag = seq + NBINS;
        const int binBlocks = (NBINS + 255) / 256;
        k_init_flat<<<binBlocks, 256, 0, stream>>>(out, seq, flag,
                                                   (const unsigned char*)alts);
        k_scatter_flat<<<(NATOMS + 255) / 256, 256, 0, stream>>>(
            contRat, desc,
            (const unsigned char*)alts, (const int*)alts, flag,
            out, out + NBINS, seq);
        k_final_flat<<<binBlocks, 256, 0, stream>>>(
            out, out + NBINS, seq, mcmax, mcmin, scmax, scmin);
    }
}